// Round 8
// baseline (484.364 us; speedup 1.0000x reference)
//
#include <hip/hip_runtime.h>

// 2-layer GRU (B=512, T=4096, H=3) + decoder, lane-parallel + layer-pipelined.
// Scalar gate math with fused h-update (one rcp for z+n combined):
//   Ez = e^{-(iz+hz)} (z = 1/(1+Ez)),  F = e^{2(gi + r*gh)} (n = (F-1)/(F+1))
//   h' = (1-z)n + z h = [Ez*(F-1) + h*(F+1)] / [(F+1)*(1+Ez)]
// Trans ops per step: 3 exp2 + 2 rcp (was 3 exp2 + 3 rcp).
//
// 8 lanes per batch element:
//   lanes 0-2 (quad 0): layer-0 hidden units j=0..2   lane 3: dummy
//   lanes 4-6 (quad 1): layer-1 hidden units j=0..2   lane 7: dummy + y-store
// Layer 1 processes step t-1 while layer 0 processes step t; hand-off via a
// masked DPP (row_shr:4, bank_mask=0xA) that overwrites only quad-1 lanes,
// so input-select costs one instruction. Decoder y lags 2 iterations.

constexpr int T = 4096;
constexpr int B = 512;
constexpr float LOG2E = 1.44269504088896340736f;

__device__ __forceinline__ float fexp2(float v) { return __builtin_amdgcn_exp2f(v); }
__device__ __forceinline__ float frcp(float v)  { return __builtin_amdgcn_rcpf(v); }

template<int CTRL>
__device__ __forceinline__ float dppf(float v) {
    return __int_as_float(
        __builtin_amdgcn_update_dpp(0, __float_as_int(v), CTRL, 0xF, 0xF, true));
}
// quad_perm broadcast of lane k within quad: ctrl = k * 0x55

// in = (quad0) ? xv : row_shr:4(hbv)  -- single masked v_mov_b32_dpp:
// bank_mask 0xA enables only lanes 4-7 / 12-15 of each row (the quad1s);
// disabled lanes keep old (= xv).
__device__ __forceinline__ float dpp_sel(float xv, float hbv) {
    return __int_as_float(__builtin_amdgcn_update_dpp(
        __float_as_int(xv), __float_as_int(hbv), 0x114, 0xF, 0xA, false));
}

// One pipeline iteration. MODE: 0 = normal, 1 = first (freeze quad-1 h),
// 2 = last (freeze quad-0 h). YV = y(i-2), valid on quad-1 lanes.
#define GRU_IT(MODE, X0, X1, X2, YV) do {                                      \
    float hb0 = dppf<0x00>(h), hb1 = dppf<0x55>(h), hb2 = dppf<0xAA>(h);       \
    float in0 = dpp_sel((X0), hb0);                                            \
    float in1 = dpp_sel((X1), hb1);                                            \
    float in2 = dpp_sel((X2), hb2);                                            \
    YV = fmaf(wd2, hb2, fmaf(wd1, hb1, fmaf(wd0, hb0, bd)));                   \
    float crx = fmaf(wir2, in2, fmaf(wir1, in1, fmaf(wir0, in0, br)));         \
    float crh = fmaf(whr2, hb2, fmaf(whr1, hb1, whr0 * hb0));                  \
    float cr  = crx + crh;                                                     \
    float czx = fmaf(wiz2, in2, fmaf(wiz1, in1, fmaf(wiz0, in0, bz)));         \
    float czh = fmaf(whz2, hb2, fmaf(whz1, hb1, whz0 * hb0));                  \
    float cz  = czx + czh;                                                     \
    float gh  = fmaf(whn2, hb2, fmaf(whn1, hb1, fmaf(whn0, hb0, bnh)));        \
    float gi  = fmaf(win2, in2, fmaf(win1, in1, fmaf(win0, in0, bni)));        \
    float Er  = fexp2(cr);                                                     \
    float rr  = frcp(1.0f + Er);                                               \
    float aa  = fmaf(rr, gh, gi);                                              \
    float F   = fexp2(aa);                                                     \
    float Ez  = fexp2(cz);                                                     \
    float Fp  = F + 1.0f;                                                      \
    float Fm  = F - 1.0f;                                                      \
    float Ezp = Ez + 1.0f;                                                     \
    float num = fmaf(h, Fp, Ez * Fm);    /* h*(F+1) + Ez*(F-1) */              \
    float hn  = num * frcp(Fp * Ezp);                                          \
    if ((MODE) == 0)      h = hn;                                              \
    else if ((MODE) == 1) h = is_q0 ? hn : h;                                  \
    else                  h = is_q0 ? h : hn;                                  \
} while (0)

__global__ __launch_bounds__(64, 1)
void gru_pipe(const float* __restrict__ x,     // [B,T,3]
              const float* __restrict__ h0,    // [2,B,3]
              const float* __restrict__ Wih,   // [2,9,3]
              const float* __restrict__ Whh,   // [2,9,3]
              const float* __restrict__ bih,   // [2,9]
              const float* __restrict__ bhh,   // [2,9]
              const float* __restrict__ Wdec,  // [1,3]
              const float* __restrict__ bdec,  // [1]
              float* __restrict__ out)         // y[B*T] then h_out[2*B*3]
{
    const int lane  = threadIdx.x;           // 0..63, block = 1 wave
    const int g8    = lane & 7;              // position within 8-lane group
    const int layer = (g8 >> 2) & 1;         // quad parity = layer
    const int jj    = g8 & 3;
    const int j     = jj > 2 ? 2 : jj;       // clamped row (dummy lanes reuse j=2)
    const bool dummy = (jj == 3);
    const bool is_q0 = (layer == 0);
    const int b = (blockIdx.x * 64 + lane) >> 3;   // batch element

    // ---- per-lane weights, pre-scaled:
    //   r/z chains carry -log2(e); n chains carry 2*log2(e); dummy lanes zeroed
    const float zm = dummy ? 0.0f : 1.0f;
    const float sR = -LOG2E * zm, sN = 2.0f * LOG2E * zm;
    const float* Wi = Wih + layer * 27;
    const float* Wh = Whh + layer * 27;
    const float* bi = bih + layer * 9;
    const float* bh = bhh + layer * 9;

    const float wir0 = Wi[j*3+0]*sR, wir1 = Wi[j*3+1]*sR, wir2 = Wi[j*3+2]*sR;
    const float wiz0 = Wi[(3+j)*3+0]*sR, wiz1 = Wi[(3+j)*3+1]*sR, wiz2 = Wi[(3+j)*3+2]*sR;
    const float win0 = Wi[(6+j)*3+0]*sN, win1 = Wi[(6+j)*3+1]*sN, win2 = Wi[(6+j)*3+2]*sN;
    const float whr0 = Wh[j*3+0]*sR, whr1 = Wh[j*3+1]*sR, whr2 = Wh[j*3+2]*sR;
    const float whz0 = Wh[(3+j)*3+0]*sR, whz1 = Wh[(3+j)*3+1]*sR, whz2 = Wh[(3+j)*3+2]*sR;
    const float whn0 = Wh[(6+j)*3+0]*sN, whn1 = Wh[(6+j)*3+1]*sN, whn2 = Wh[(6+j)*3+2]*sN;
    const float br  = (bi[j] + bh[j]) * sR;
    const float bz  = (bi[3+j] + bh[3+j]) * sR;
    const float bni = bi[6+j] * sN;
    const float bnh = bh[6+j] * sN;
    const float wd0 = Wdec[0], wd1 = Wdec[1], wd2 = Wdec[2], bd = bdec[0];

    float h = dummy ? 0.0f : h0[layer * B * 3 + b * 3 + j];

    const float4* xb = reinterpret_cast<const float4*>(x + (size_t)b * T * 3);
    float* yo = out + (size_t)b * T;

    // double-buffered chunk registers: cu = chunk t, nx = chunk t+1
    float4 nx0 = xb[0], nx1 = xb[1], nx2 = xb[2];
    float4 cu0 = xb[3], cu1 = xb[4], cu2 = xb[5];
    float y0, y1, y2, y3, p2, p3;

    // ---- chunk 0 (prologue: freeze layer-1 h at i=0) ----
    {
        GRU_IT(1, nx0.x, nx0.y, nx0.z, y0);   // i=0
        GRU_IT(0, nx0.w, nx1.x, nx1.y, y1);   // i=1
        GRU_IT(0, nx1.z, nx1.w, nx2.x, y2);   // i=2 -> y(0)
        GRU_IT(0, nx2.y, nx2.z, nx2.w, y3);   // i=3 -> y(1)
        p2 = y2; p3 = y3;                     // carry y(0), y(1)
    }
    nx0 = xb[6]; nx1 = xb[7]; nx2 = xb[8];    // chunk 2
    // invariant entering loop (tc=1): cu = d(1), nx = d(2)

    #pragma unroll 1
    for (int tc = 1; tc <= 1021; tc += 2) {
        // entry: cu = d(tc), nx = d(tc+1)
        const float4* pfa = xb + (tc + 2) * 3;               // d(tc+2), in-bounds
        float4 La0 = pfa[0], La1 = pfa[1], La2 = pfa[2];
        // ---- chunk tc (from cu) ----
        GRU_IT(0, cu0.x, cu0.y, cu0.z, y0);
        GRU_IT(0, cu0.w, cu1.x, cu1.y, y1);
        GRU_IT(0, cu1.z, cu1.w, cu2.x, y2);
        GRU_IT(0, cu2.y, cu2.z, cu2.w, y3);
        if (g8 == 7) {
            float4 q; q.x = p2; q.y = p3; q.z = y0; q.w = y1;
            *(float4*)(yo + 4 * tc - 4) = q;                 // y(4tc-4 .. 4tc-1)
        }
        p2 = y2; p3 = y3;
        const float4* pfb = xb + (((tc + 3) & 1023) * 3);    // d(tc+3), masked
        float4 Lb0 = pfb[0], Lb1 = pfb[1], Lb2 = pfb[2];
        // ---- chunk tc+1 (from nx) ----
        GRU_IT(0, nx0.x, nx0.y, nx0.z, y0);
        GRU_IT(0, nx0.w, nx1.x, nx1.y, y1);
        GRU_IT(0, nx1.z, nx1.w, nx2.x, y2);
        GRU_IT(0, nx2.y, nx2.z, nx2.w, y3);
        if (g8 == 7) {
            float4 q; q.x = p2; q.y = p3; q.z = y0; q.w = y1;
            *(float4*)(yo + 4 * tc) = q;                     // y(4tc .. 4tc+3)
        }
        p2 = y2; p3 = y3;
        cu0 = La0; cu1 = La1; cu2 = La2;                     // d(tc+2)
        nx0 = Lb0; nx1 = Lb1; nx2 = Lb2;                     // d(tc+3)
    }
    // exit: cu = d(1023), nx = wrapped (unused)

    // ---- chunk 1023 ----
    GRU_IT(0, cu0.x, cu0.y, cu0.z, y0);
    GRU_IT(0, cu0.w, cu1.x, cu1.y, y1);
    GRU_IT(0, cu1.z, cu1.w, cu2.x, y2);
    GRU_IT(0, cu2.y, cu2.z, cu2.w, y3);
    if (g8 == 7) {
        float4 q; q.x = p2; q.y = p3; q.z = y0; q.w = y1;
        *(float4*)(yo + 4088) = q;                           // y(4088 .. 4091)
    }
    p2 = y2; p3 = y3;                                        // y(4092), y(4093)

    // ---- epilogue ----
    GRU_IT(2, 0.0f, 0.0f, 0.0f, y0);       // i=T: layer-1 finishes h1(T-1); y(T-2)
    {
        float hb0 = dppf<0x00>(h), hb1 = dppf<0x55>(h), hb2 = dppf<0xAA>(h);
        y1 = fmaf(wd2, hb2, fmaf(wd1, hb1, fmaf(wd0, hb0, bd)));   // y(T-1)
    }
    if (g8 == 7) {
        float4 q; q.x = p2; q.y = p3; q.z = y0; q.w = y1;
        *(float4*)(yo + 4092) = q;                           // y(4092 .. 4095)
    }

    // final hidden states
    if (!dummy) out[B * T + (layer * B + b) * 3 + j] = h;
}

extern "C" void kernel_launch(void* const* d_in, const int* in_sizes, int n_in,
                              void* d_out, int out_size, void* d_ws, size_t ws_size,
                              hipStream_t stream) {
    const float* x    = (const float*)d_in[0];
    const float* h0   = (const float*)d_in[1];
    const float* Wih  = (const float*)d_in[2];
    const float* Whh  = (const float*)d_in[3];
    const float* bih  = (const float*)d_in[4];
    const float* bhh  = (const float*)d_in[5];
    const float* Wdec = (const float*)d_in[6];
    const float* bdec = (const float*)d_in[7];
    float* out = (float*)d_out;

    gru_pipe<<<(B * 8) / 64, 64, 0, stream>>>(x, h0, Wih, Whh, bih, bhh,
                                              Wdec, bdec, out);
}

// Round 9
// 457.810 us; speedup vs baseline: 1.0580x; 1.0580x over previous
//
#include <hip/hip_runtime.h>

// 2-layer GRU (B=512, T=4096, H=3) + decoder.
// 16 lanes per batch element, gate-role split, layer-pipelined:
//   quad0 (lanes 0-3):   L0 OWNER lanes, unit j = lane&3 (j==3 dummy)
//                        computes cz, gi, z=rcp(1+Ez), h-update; HOLDS h.
//   quad1 (lanes 4-7):   L0 AUX lanes, unit j = 3-(lane&3) (kk==0 dummy)
//                        computes cr, gh, r=rcp(1+Er), m = r*gh.
//   quad2 (8-11):        L1 OWNER (lane11 = decoder: dotA = Wdec·hb + bdec)
//   quad3 (12-15):       L1 AUX
// Uniform stream; per-lane weights select the gate. Trans/step: 2 exp2 + 2 rcp
// (shared slots: E is Ez on owner, Er on aux). Layer 1 lags layer 0 by one
// step (pipeline); decoder y lags 2.
// Cross-lane: quad_perm broadcasts (h lives on owner quads);
//   row_shr:4  (bank 0xA): hb -> aux quads            [direction HW-verified]
//   row_shr:8  (bank 0xC): L0 hb -> L1 lanes' input   [same verified family]
//   row_half_mirror (bank 0x5): m aux->owner (involution; aux units mirrored
//                               so lane 7-j / 15-(j+8) is unit j's partner)

constexpr int T = 4096;
constexpr int B = 512;
constexpr float LOG2E = 1.44269504088896340736f;

__device__ __forceinline__ float fexp2(float v) { return __builtin_amdgcn_exp2f(v); }
__device__ __forceinline__ float frcp(float v)  { return __builtin_amdgcn_rcpf(v); }

template<int CTRL>
__device__ __forceinline__ float dppf(float v) {   // quad_perm broadcast, bc=1
    return __int_as_float(
        __builtin_amdgcn_update_dpp(0, __float_as_int(v), CTRL, 0xF, 0xF, true));
}
template<int CTRL, int BANK>
__device__ __forceinline__ float dppm(float oldv, float src) {  // masked move
    return __int_as_float(__builtin_amdgcn_update_dpp(
        __float_as_int(oldv), __float_as_int(src), CTRL, 0xF, BANK, false));
}

// One pipeline iteration. MODE: 0 normal, 1 first (freeze L1), 2 last
// (freeze L0). YV = y(i-2), valid on decoder lanes (g16==11).
#define GRU_IT(MODE, X0, X1, X2, YV) do {                                      \
    float b0 = dppf<0x00>(h), b1 = dppf<0x55>(h), b2 = dppf<0xAA>(h);          \
    b0 = dppm<0x114, 0xA>(b0, b0);   /* aux quads <- owner hb */               \
    b1 = dppm<0x114, 0xA>(b1, b1);                                             \
    b2 = dppm<0x114, 0xA>(b2, b2);                                             \
    float in0 = dppm<0x118, 0xC>((X0), b0);  /* L1 lanes: in = L0 hb */        \
    float in1 = dppm<0x118, 0xC>((X1), b1);                                    \
    float in2 = dppm<0x118, 0xC>((X2), b2);                                    \
    float cx  = fmaf(uA2, in2, fmaf(uA1, in1, fmaf(uA0, in0, bA)));            \
    float chh = fmaf(vA2, b2, fmaf(vA1, b1, vA0 * b0));                        \
    float c   = cx + chh;            /* owner: cz; aux: cr; lane11: y */       \
    YV = c;                                                                    \
    float gx  = fmaf(uB2, in2, fmaf(uB1, in1, fmaf(uB0, in0, bB)));            \
    float ghh = fmaf(vB2, b2, fmaf(vB1, b1, vB0 * b0));                        \
    float g   = gx + ghh;            /* owner: gi_s; aux: gh_s */              \
    float E   = fexp2(c);            /* owner: Ez;  aux: Er */                 \
    float w   = frcp(1.0f + E);      /* owner: z;   aux: r  */                 \
    float m   = w * g;               /* aux: r*gh_s */                         \
    float mm  = dppm<0x141, 0x5>(m, m);  /* owner <- mirrored aux partner */   \
    float aa  = mm + g;              /* owner: r*gh_s + gi_s */                \
    float F   = fexp2(aa);                                                     \
    float nn  = fmaf(-2.0f, frcp(F + 1.0f), 1.0f);   /* tanh */                \
    float hn  = fmaf(w, h - nn, nn); /* z*(h-n)+n */                           \
    if ((MODE) == 0)      h = hn;                                              \
    else if ((MODE) == 1) h = is_L0 ? hn : h;                                  \
    else                  h = is_L0 ? h : hn;                                  \
} while (0)

__global__ __launch_bounds__(64, 1)
void gru_pipe(const float* __restrict__ x,     // [B,T,3]
              const float* __restrict__ h0,    // [2,B,3]
              const float* __restrict__ Wih,   // [2,9,3]
              const float* __restrict__ Whh,   // [2,9,3]
              const float* __restrict__ bih,   // [2,9]
              const float* __restrict__ bhh,   // [2,9]
              const float* __restrict__ Wdec,  // [1,3]
              const float* __restrict__ bdec,  // [1]
              float* __restrict__ out)         // y[B*T] then h_out[2*B*3]
{
    const int lane  = threadIdx.x;             // 0..63, block = 1 wave
    const int g16   = lane & 15;
    const int quad  = g16 >> 2;                // 0..3
    const int layer = quad >> 1;
    const bool ownr = (quad & 1) == 0;
    const int kk    = g16 & 3;
    const bool isdec = (g16 == 11);
    const bool is_L0 = (g16 < 8);
    const bool dlane = isdec;
    const int b = (blockIdx.x * 64 + lane) >> 4;    // batch element

    // unit index: owner lane kk -> unit kk; aux lane kk -> unit 3-kk (mirrored)
    const int  uj    = ownr ? (kk < 3 ? kk : 0) : (kk > 0 ? 3 - kk : 0);
    const bool valid = ownr ? (kk < 3) : (kk > 0);
    const float zm = valid ? 1.0f : 0.0f;
    const float sR = -LOG2E * zm;              // r/z chains carry -log2(e)
    const float sN = 2.0f * LOG2E * zm;        // n chain carries 2*log2(e)

    const float* Wi = Wih + layer * 27;
    const float* Wh = Whh + layer * 27;
    const float* bi = bih + layer * 9;
    const float* bh = bhh + layer * 9;

    // dotA: owner -> z-gate row (3+uj); aux -> r-gate row (uj)
    const int rA = ownr ? (3 + uj) : uj;
    float uA0 = Wi[rA*3+0]*sR, uA1 = Wi[rA*3+1]*sR, uA2 = Wi[rA*3+2]*sR;
    float vA0 = Wh[rA*3+0]*sR, vA1 = Wh[rA*3+1]*sR, vA2 = Wh[rA*3+2]*sR;
    float bA  = (bi[rA] + bh[rA]) * sR;
    // dotB: owner -> gi (x-side of n row); aux -> gh (h-side of n row)
    const int rN = 6 + uj;
    float uB0, uB1, uB2, vB0, vB1, vB2, bB;
    if (ownr) {
        uB0 = Wi[rN*3+0]*sN; uB1 = Wi[rN*3+1]*sN; uB2 = Wi[rN*3+2]*sN;
        vB0 = 0.0f; vB1 = 0.0f; vB2 = 0.0f;
        bB  = bi[rN]*sN;
    } else {
        uB0 = 0.0f; uB1 = 0.0f; uB2 = 0.0f;
        vB0 = Wh[rN*3+0]*sN; vB1 = Wh[rN*3+1]*sN; vB2 = Wh[rN*3+2]*sN;
        bB  = bh[rN]*sN;
    }
    if (isdec) {   // lane11: dotA = decoder (reads L1 hb); dotB already zeroed
        uA0 = uA1 = uA2 = 0.0f;
        vA0 = Wdec[0]; vA1 = Wdec[1]; vA2 = Wdec[2];
        bA  = bdec[0];
    }

    float h = (ownr && kk < 3) ? h0[layer * B * 3 + b * 3 + kk] : 0.0f;

    const float4* xb = reinterpret_cast<const float4*>(x + (size_t)b * T * 3);
    float* yo = out + (size_t)b * T;

    // double-buffered chunk registers: cu = chunk t, nx = chunk t+1
    float4 nx0 = xb[0], nx1 = xb[1], nx2 = xb[2];
    float4 cu0 = xb[3], cu1 = xb[4], cu2 = xb[5];
    float y0, y1, y2, y3, p2, p3;

    // ---- chunk 0 (prologue: freeze L1 h at i=0) ----
    {
        GRU_IT(1, nx0.x, nx0.y, nx0.z, y0);   // i=0
        GRU_IT(0, nx0.w, nx1.x, nx1.y, y1);   // i=1
        GRU_IT(0, nx1.z, nx1.w, nx2.x, y2);   // i=2 -> y(0)
        GRU_IT(0, nx2.y, nx2.z, nx2.w, y3);   // i=3 -> y(1)
        p2 = y2; p3 = y3;                     // carry y(0), y(1)
    }
    nx0 = xb[6]; nx1 = xb[7]; nx2 = xb[8];    // chunk 2
    // invariant entering loop (tc=1): cu = d(1), nx = d(2)

    #pragma unroll 1
    for (int tc = 1; tc <= 1021; tc += 2) {
        // entry: cu = d(tc), nx = d(tc+1)
        const float4* pfa = xb + (tc + 2) * 3;               // d(tc+2), in-bounds
        float4 La0 = pfa[0], La1 = pfa[1], La2 = pfa[2];
        // ---- chunk tc (from cu) ----
        GRU_IT(0, cu0.x, cu0.y, cu0.z, y0);
        GRU_IT(0, cu0.w, cu1.x, cu1.y, y1);
        GRU_IT(0, cu1.z, cu1.w, cu2.x, y2);
        GRU_IT(0, cu2.y, cu2.z, cu2.w, y3);
        if (dlane) {
            float4 q; q.x = p2; q.y = p3; q.z = y0; q.w = y1;
            *(float4*)(yo + 4 * tc - 4) = q;                 // y(4tc-4 .. 4tc-1)
        }
        p2 = y2; p3 = y3;
        const float4* pfb = xb + (((tc + 3) & 1023) * 3);    // d(tc+3), masked
        float4 Lb0 = pfb[0], Lb1 = pfb[1], Lb2 = pfb[2];
        // ---- chunk tc+1 (from nx) ----
        GRU_IT(0, nx0.x, nx0.y, nx0.z, y0);
        GRU_IT(0, nx0.w, nx1.x, nx1.y, y1);
        GRU_IT(0, nx1.z, nx1.w, nx2.x, y2);
        GRU_IT(0, nx2.y, nx2.z, nx2.w, y3);
        if (dlane) {
            float4 q; q.x = p2; q.y = p3; q.z = y0; q.w = y1;
            *(float4*)(yo + 4 * tc) = q;                     // y(4tc .. 4tc+3)
        }
        p2 = y2; p3 = y3;
        cu0 = La0; cu1 = La1; cu2 = La2;                     // d(tc+2)
        nx0 = Lb0; nx1 = Lb1; nx2 = Lb2;                     // d(tc+3)
    }
    // exit: cu = d(1023), nx = wrapped (unused)

    // ---- chunk 1023 ----
    GRU_IT(0, cu0.x, cu0.y, cu0.z, y0);
    GRU_IT(0, cu0.w, cu1.x, cu1.y, y1);
    GRU_IT(0, cu1.z, cu1.w, cu2.x, y2);
    GRU_IT(0, cu2.y, cu2.z, cu2.w, y3);
    if (dlane) {
        float4 q; q.x = p2; q.y = p3; q.z = y0; q.w = y1;
        *(float4*)(yo + 4088) = q;                           // y(4088 .. 4091)
    }
    p2 = y2; p3 = y3;                                        // y(4092), y(4093)

    // ---- epilogue ----
    GRU_IT(2, 0.0f, 0.0f, 0.0f, y0);       // i=T: L1 finishes h1(T-1); y(T-2)
    {
        float b0 = dppf<0x00>(h), b1 = dppf<0x55>(h), b2 = dppf<0xAA>(h);
        y1 = fmaf(vA2, b2, fmaf(vA1, b1, fmaf(vA0, b0, bA)));  // lane11: y(T-1)
    }
    if (dlane) {
        float4 q; q.x = p2; q.y = p3; q.z = y0; q.w = y1;
        *(float4*)(yo + 4092) = q;                           // y(4092 .. 4095)
    }

    // final hidden states (owner lanes hold h)
    if (ownr && kk < 3) out[B * T + (layer * B + b) * 3 + kk] = h;
}

extern "C" void kernel_launch(void* const* d_in, const int* in_sizes, int n_in,
                              void* d_out, int out_size, void* d_ws, size_t ws_size,
                              hipStream_t stream) {
    const float* x    = (const float*)d_in[0];
    const float* h0   = (const float*)d_in[1];
    const float* Wih  = (const float*)d_in[2];
    const float* Whh  = (const float*)d_in[3];
    const float* bih  = (const float*)d_in[4];
    const float* bhh  = (const float*)d_in[5];
    const float* Wdec = (const float*)d_in[6];
    const float* bdec = (const float*)d_in[7];
    float* out = (float*)d_out;

    gru_pipe<<<(B * 16) / 64, 64, 0, stream>>>(x, h0, Wih, Whh, bih, bhh,
                                               Wdec, bdec, out);
}